// Round 3
// baseline (1362.151 us; speedup 1.0000x reference)
//
#include <hip/hip_runtime.h>
#include <math.h>

#define NN 100000
#define NE 1600000
#define F_IN 602
#define H1 8
#define C1 8
#define F_MID 64   // H1*C1
#define NC 41
#define NEG_SLOPE 0.2f

// ---------------- GEMM1: h1 = x @ W1  [N,602] x [602,64] ----------------
// 64x64 tile, K-tile 32, 4x4 register blocking per thread (16x16 thread grid).
__global__ __launch_bounds__(256) void gemm1_kernel(
    const float* __restrict__ x, const float* __restrict__ W,
    float* __restrict__ h, int N)
{
    __shared__ float xs[32][68];   // [kk][row], stride 68 floats = 272B (16B aligned)
    __shared__ float ws[32][64];   // [kk][col]
    int t  = threadIdx.x;
    int tr = t >> 4;               // 0..15 -> rows tr*4..tr*4+3
    int tc = t & 15;               // 0..15 -> cols tc*4..tc*4+3
    int n0 = blockIdx.x * 64;
    float acc[4][4] = {};

    for (int k0 = 0; k0 < F_IN; k0 += 32) {
        // stage x tile: 64 rows x 32 k (transposed to k-major)
        {
            int kk = t & 31;
            int rr = t >> 5;
            int k = k0 + kk;
            #pragma unroll
            for (int i = 0; i < 8; ++i) {
                int r = rr + i * 8;
                int n = n0 + r;
                xs[kk][r] = (n < N && k < F_IN) ? x[n * F_IN + k] : 0.f;
            }
        }
        // stage W tile: 32 k x 64 cols  (2048 floats = 256 threads x 8)
        #pragma unroll
        for (int i = 0; i < 8; ++i) {
            int idx = t + i * 256;
            int kk = idx >> 6, jj = idx & 63;
            int k = k0 + kk;
            ws[kk][jj] = (k < F_IN) ? W[k * F_MID + jj] : 0.f;
        }
        __syncthreads();
        #pragma unroll
        for (int kk = 0; kk < 32; ++kk) {
            float xv[4], wv[4];
            #pragma unroll
            for (int u = 0; u < 4; ++u) xv[u] = xs[kk][tr * 4 + u];
            #pragma unroll
            for (int v = 0; v < 4; ++v) wv[v] = ws[kk][tc * 4 + v];
            #pragma unroll
            for (int u = 0; u < 4; ++u)
                #pragma unroll
                for (int v = 0; v < 4; ++v)
                    acc[u][v] += xv[u] * wv[v];
        }
        __syncthreads();
    }
    #pragma unroll
    for (int u = 0; u < 4; ++u) {
        int n = n0 + tr * 4 + u;
        if (n < N) {
            #pragma unroll
            for (int v = 0; v < 4; ++v)
                h[n * F_MID + tc * 4 + v] = acc[u][v];
        }
    }
}

// ---------------- attention coefficients layer 1 ----------------
__global__ void attn1_kernel(const float* __restrict__ h,
                             const float* __restrict__ attS,
                             const float* __restrict__ attD,
                             float* __restrict__ asrc, float* __restrict__ adst, int N)
{
    int idx = blockIdx.x * blockDim.x + threadIdx.x;   // n*8 + head
    if (idx >= N * H1) return;
    int n = idx >> 3, hh = idx & 7;
    float s = 0.f, d = 0.f;
    #pragma unroll
    for (int c = 0; c < C1; ++c) {
        float v = h[n * F_MID + hh * C1 + c];
        s += v * attS[hh * C1 + c];
        d += v * attD[hh * C1 + c];
    }
    asrc[idx] = s;
    adst[idx] = d;
}

// ---------------- CSR build ----------------
__global__ void deg_kernel(const int* __restrict__ dst, int* __restrict__ deg, int E)
{
    int e = blockIdx.x * blockDim.x + threadIdx.x;
    if (e < E) atomicAdd(&deg[dst[e]], 1);
}

__global__ __launch_bounds__(1024) void scan_kernel(const int* __restrict__ deg,
                                                    int* __restrict__ offs, int N, int E)
{
    __shared__ int part[1024];
    __shared__ int pref[1024];
    int t = threadIdx.x;
    int chunk = (N + 1023) / 1024;
    int b = t * chunk, e = min(N, b + chunk);
    int s = 0;
    for (int i = b; i < e; ++i) s += deg[i];
    part[t] = s;
    __syncthreads();
    if (t == 0) {
        int run = 0;
        for (int i = 0; i < 1024; ++i) { pref[i] = run; run += part[i]; }
    }
    __syncthreads();
    int run = pref[t];
    for (int i = b; i < e; ++i) { offs[i] = run; run += deg[i]; }
    if (t == 1023) offs[N] = E;
}

__global__ void scatter_kernel(const int* __restrict__ src, const int* __restrict__ dst,
                               const int* __restrict__ offs, int* __restrict__ cursor,
                               int* __restrict__ srcs, int E)
{
    int e = blockIdx.x * blockDim.x + threadIdx.x;
    if (e < E) {
        int d = dst[e];
        int pos = offs[d] + atomicAdd(&cursor[d], 1);
        srcs[pos] = src[e];
    }
}

// ---------------- layer-1 aggregation + ELU (one wave per node) ----------------
__global__ void agg1_kernel(const int* __restrict__ offs, const int* __restrict__ srcs,
                            const float* __restrict__ h1,
                            const float* __restrict__ asrc, const float* __restrict__ adst,
                            const float* __restrict__ b1,
                            float* __restrict__ out1, int N)
{
    int wave = (blockIdx.x * blockDim.x + threadIdx.x) >> 6;
    int lane = threadIdx.x & 63;
    if (wave >= N) return;
    int n = wave;
    int hh = lane >> 3;                 // head
    int beg = offs[n], end = offs[n + 1];
    float ad = adst[n * H1 + hh];

    float mx = -INFINITY;
    for (int i = beg; i < end; ++i) {
        float e = asrc[srcs[i] * H1 + hh] + ad;
        e = e >= 0.f ? e : NEG_SLOPE * e;
        mx = fmaxf(mx, e);
    }
    float den = 0.f;
    for (int i = beg; i < end; ++i) {
        float e = asrc[srcs[i] * H1 + hh] + ad;
        e = e >= 0.f ? e : NEG_SLOPE * e;
        den += __expf(e - mx);
    }
    float inv = 1.f / (den + 1e-16f);
    float acc = 0.f;
    for (int i = beg; i < end; ++i) {
        int s = srcs[i];
        float e = asrc[s * H1 + hh] + ad;
        e = e >= 0.f ? e : NEG_SLOPE * e;
        float w = __expf(e - mx) * inv;
        acc += h1[s * F_MID + lane] * w;
    }
    float v = acc + b1[lane];
    out1[n * F_MID + lane] = v > 0.f ? v : expm1f(v);   // ELU
}

// ---------------- GEMM2: h2 = out1 @ W2  [N,64] x [64,41] ----------------
__global__ __launch_bounds__(256) void gemm2_kernel(
    const float* __restrict__ out1, const float* __restrict__ W2,
    float* __restrict__ h2, int N)
{
    __shared__ float ws[F_MID * NC];
    for (int i = threadIdx.x; i < F_MID * NC; i += 256) ws[i] = W2[i];
    __syncthreads();
    int idx = blockIdx.x * blockDim.x + threadIdx.x;
    if (idx >= N * NC) return;
    int n = idx / NC, j = idx % NC;
    const float* row = out1 + n * F_MID;
    float acc = 0.f;
    #pragma unroll
    for (int k = 0; k < F_MID; ++k) acc += row[k] * ws[k * NC + j];
    h2[idx] = acc;
}

__global__ void attn2_kernel(const float* __restrict__ h2,
                             const float* __restrict__ attS,
                             const float* __restrict__ attD,
                             float* __restrict__ asrc, float* __restrict__ adst, int N)
{
    int n = blockIdx.x * blockDim.x + threadIdx.x;
    if (n >= N) return;
    float s = 0.f, d = 0.f;
    #pragma unroll
    for (int j = 0; j < NC; ++j) {
        float v = h2[n * NC + j];
        s += v * attS[j];
        d += v * attD[j];
    }
    asrc[n] = s;
    adst[n] = d;
}

// ---------------- layer-2 aggregation + log_softmax (one wave per node) ----------------
__global__ void agg2_kernel(const int* __restrict__ offs, const int* __restrict__ srcs,
                            const float* __restrict__ h2,
                            const float* __restrict__ asrc, const float* __restrict__ adst,
                            const float* __restrict__ b2,
                            float* __restrict__ out, int N)
{
    int wave = (blockIdx.x * blockDim.x + threadIdx.x) >> 6;
    int lane = threadIdx.x & 63;
    if (wave >= N) return;
    int n = wave;
    int beg = offs[n], end = offs[n + 1];
    float ad = adst[n];

    float mx = -INFINITY;
    for (int i = beg; i < end; ++i) {
        float e = asrc[srcs[i]] + ad;
        e = e >= 0.f ? e : NEG_SLOPE * e;
        mx = fmaxf(mx, e);
    }
    float den = 0.f;
    for (int i = beg; i < end; ++i) {
        float e = asrc[srcs[i]] + ad;
        e = e >= 0.f ? e : NEG_SLOPE * e;
        den += __expf(e - mx);
    }
    float inv = 1.f / (den + 1e-16f);
    float acc = 0.f;
    for (int i = beg; i < end; ++i) {
        int s = srcs[i];
        float e = asrc[s] + ad;
        e = e >= 0.f ? e : NEG_SLOPE * e;
        float w = __expf(e - mx) * inv;
        if (lane < NC) acc += h2[s * NC + lane] * w;
    }
    // v = logits; log_softmax across lanes 0..40
    float v = (lane < NC) ? acc + b2[lane] : -INFINITY;
    float m = v;
    #pragma unroll
    for (int o = 32; o > 0; o >>= 1) m = fmaxf(m, __shfl_xor(m, o));
    float ex = (lane < NC) ? __expf(v - m) : 0.f;
    float S = ex;
    #pragma unroll
    for (int o = 32; o > 0; o >>= 1) S += __shfl_xor(S, o);
    if (lane < NC) out[n * NC + lane] = v - m - logf(S);
}

// ---------------- launch ----------------
extern "C" void kernel_launch(void* const* d_in, const int* in_sizes, int n_in,
                              void* d_out, int out_size, void* d_ws, size_t ws_size,
                              hipStream_t stream)
{
    const float* x     = (const float*)d_in[0];
    const int*   ei    = (const int*)  d_in[1];
    const float* W1    = (const float*)d_in[2];
    const float* attS1 = (const float*)d_in[3];
    const float* attD1 = (const float*)d_in[4];
    const float* b1    = (const float*)d_in[5];
    const float* W2    = (const float*)d_in[6];
    const float* attS2 = (const float*)d_in[7];
    const float* attD2 = (const float*)d_in[8];
    const float* b2    = (const float*)d_in[9];
    float* out = (float*)d_out;

    const int N = NN, E = NE;
    const int* src = ei;        // edge_index row 0
    const int* dst = ei + E;    // edge_index row 1

    char* p = (char*)d_ws;
    auto alloc = [&](size_t bytes) { char* r = p; p += (bytes + 255) & ~255ull; return r; };
    float* h1    = (float*)alloc((size_t)N * F_MID * 4);
    float* asrc1 = (float*)alloc((size_t)N * H1 * 4);
    float* adst1 = (float*)alloc((size_t)N * H1 * 4);
    float* out1  = (float*)alloc((size_t)N * F_MID * 4);
    float* h2    = (float*)alloc((size_t)N * NC * 4);
    float* asrc2 = (float*)alloc((size_t)N * 4);
    float* adst2 = (float*)alloc((size_t)N * 4);
    int*   deg   = (int*)alloc((size_t)2 * N * 4);    // deg + cursor contiguous
    int*   cursor= deg + N;
    int*   offs  = (int*)alloc((size_t)(N + 1) * 4);
    int*   srcs  = (int*)alloc((size_t)E * 4);

    hipMemsetAsync(deg, 0, (size_t)2 * N * 4, stream);

    gemm1_kernel<<<(N + 63) / 64, 256, 0, stream>>>(x, W1, h1, N);
    attn1_kernel<<<(N * H1 + 255) / 256, 256, 0, stream>>>(h1, attS1, attD1, asrc1, adst1, N);
    deg_kernel<<<(E + 255) / 256, 256, 0, stream>>>(dst, deg, E);
    scan_kernel<<<1, 1024, 0, stream>>>(deg, offs, N, E);
    scatter_kernel<<<(E + 255) / 256, 256, 0, stream>>>(src, dst, offs, cursor, srcs, E);
    agg1_kernel<<<(N * 64 + 255) / 256, 256, 0, stream>>>(offs, srcs, h1, asrc1, adst1, b1, out1, N);
    gemm2_kernel<<<(N * NC + 255) / 256, 256, 0, stream>>>(out1, W2, h2, N);
    attn2_kernel<<<(N + 255) / 256, 256, 0, stream>>>(h2, attS2, attD2, asrc2, adst2, N);
    agg2_kernel<<<(N * 64 + 255) / 256, 256, 0, stream>>>(offs, srcs, h2, asrc2, adst2, b2, out, N);
}

// Round 4
// 802.785 us; speedup vs baseline: 1.6968x; 1.6968x over previous
//
#include <hip/hip_runtime.h>
#include <math.h>

#define NN 100000
#define NE 1600000
#define F_IN 602
#define H1 8
#define C1 8
#define F_MID 64   // H1*C1
#define NC 41
#define NEG_SLOPE 0.2f

#define LRELU(x) fmaxf((x), NEG_SLOPE * (x))

// ---------------- GEMM1: h1 = x @ W1  [N,602] x [602,64] ----------------
__global__ __launch_bounds__(256) void gemm1_kernel(
    const float* __restrict__ x, const float* __restrict__ W,
    float* __restrict__ h, int N)
{
    __shared__ float xs[32][68];
    __shared__ float ws[32][64];
    int t  = threadIdx.x;
    int tr = t >> 4;
    int tc = t & 15;
    int n0 = blockIdx.x * 64;
    float acc[4][4] = {};

    for (int k0 = 0; k0 < F_IN; k0 += 32) {
        {
            int kk = t & 31;
            int rr = t >> 5;
            int k = k0 + kk;
            #pragma unroll
            for (int i = 0; i < 8; ++i) {
                int r = rr + i * 8;
                int n = n0 + r;
                xs[kk][r] = (n < N && k < F_IN) ? x[n * F_IN + k] : 0.f;
            }
        }
        #pragma unroll
        for (int i = 0; i < 8; ++i) {
            int idx = t + i * 256;
            int kk = idx >> 6, jj = idx & 63;
            int k = k0 + kk;
            ws[kk][jj] = (k < F_IN) ? W[k * F_MID + jj] : 0.f;
        }
        __syncthreads();
        #pragma unroll
        for (int kk = 0; kk < 32; ++kk) {
            float xv[4], wv[4];
            #pragma unroll
            for (int u = 0; u < 4; ++u) xv[u] = xs[kk][tr * 4 + u];
            #pragma unroll
            for (int v = 0; v < 4; ++v) wv[v] = ws[kk][tc * 4 + v];
            #pragma unroll
            for (int u = 0; u < 4; ++u)
                #pragma unroll
                for (int v = 0; v < 4; ++v)
                    acc[u][v] += xv[u] * wv[v];
        }
        __syncthreads();
    }
    #pragma unroll
    for (int u = 0; u < 4; ++u) {
        int n = n0 + tr * 4 + u;
        if (n < N) {
            #pragma unroll
            for (int v = 0; v < 4; ++v)
                h[n * F_MID + tc * 4 + v] = acc[u][v];
        }
    }
}

// ---------------- attention coefficients layer 1 ----------------
__global__ void attn1_kernel(const float* __restrict__ h,
                             const float* __restrict__ attS,
                             const float* __restrict__ attD,
                             float* __restrict__ asrc, float* __restrict__ adst, int N)
{
    int idx = blockIdx.x * blockDim.x + threadIdx.x;   // n*8 + head
    if (idx >= N * H1) return;
    int n = idx >> 3, hh = idx & 7;
    float s = 0.f, d = 0.f;
    #pragma unroll
    for (int c = 0; c < C1; ++c) {
        float v = h[n * F_MID + hh * C1 + c];
        s += v * attS[hh * C1 + c];
        d += v * attD[hh * C1 + c];
    }
    asrc[idx] = s;
    adst[idx] = d;
}

// ---------------- CSR build ----------------
__global__ void deg_kernel(const int* __restrict__ dst, int* __restrict__ deg, int E)
{
    int e = blockIdx.x * blockDim.x + threadIdx.x;
    if (e < E) atomicAdd(&deg[dst[e]], 1);
}

__global__ __launch_bounds__(1024) void scan_kernel(const int* __restrict__ deg,
                                                    int* __restrict__ offs, int N, int E)
{
    __shared__ int part[1024];
    __shared__ int pref[1024];
    int t = threadIdx.x;
    int chunk = (N + 1023) / 1024;
    int b = t * chunk, e = min(N, b + chunk);
    int s = 0;
    for (int i = b; i < e; ++i) s += deg[i];
    part[t] = s;
    __syncthreads();
    if (t == 0) {
        int run = 0;
        for (int i = 0; i < 1024; ++i) { pref[i] = run; run += part[i]; }
    }
    __syncthreads();
    int run = pref[t];
    for (int i = b; i < e; ++i) { offs[i] = run; run += deg[i]; }
    if (t == 1023) offs[N] = E;
}

__global__ void scatter_kernel(const int* __restrict__ src, const int* __restrict__ dst,
                               const int* __restrict__ offs, int* __restrict__ cursor,
                               int* __restrict__ srcs, int E)
{
    int e = blockIdx.x * blockDim.x + threadIdx.x;
    if (e < E) {
        int d = dst[e];
        int pos = offs[d] + atomicAdd(&cursor[d], 1);
        srcs[pos] = src[e];
    }
}

// ------- layer-1 aggregation + ELU: one wave per node, online softmax, 4-edge batches -------
__global__ void agg1_kernel(const int* __restrict__ offs, const int* __restrict__ srcs,
                            const float* __restrict__ h1,
                            const float* __restrict__ asrc, const float* __restrict__ adst,
                            const float* __restrict__ b1,
                            float* __restrict__ out1, int N)
{
    int wave = (blockIdx.x * blockDim.x + threadIdx.x) >> 6;
    int lane = threadIdx.x & 63;
    if (wave >= N) return;
    int n = wave;
    int hh = lane >> 3;                 // head
    int beg = offs[n], end = offs[n + 1];
    float ad = adst[n * H1 + hh];

    float m = -INFINITY, den = 0.f, acc = 0.f;
    int i = beg;
    for (; i + 4 <= end; i += 4) {
        int s0 = srcs[i], s1 = srcs[i + 1], s2 = srcs[i + 2], s3 = srcs[i + 3];
        float a0 = asrc[s0 * H1 + hh], a1 = asrc[s1 * H1 + hh];
        float a2 = asrc[s2 * H1 + hh], a3 = asrc[s3 * H1 + hh];
        float v0 = h1[s0 * F_MID + lane], v1 = h1[s1 * F_MID + lane];
        float v2 = h1[s2 * F_MID + lane], v3 = h1[s3 * F_MID + lane];
        float e0 = LRELU(a0 + ad), e1 = LRELU(a1 + ad);
        float e2 = LRELU(a2 + ad), e3 = LRELU(a3 + ad);
        float m4 = fmaxf(fmaxf(e0, e1), fmaxf(e2, e3));
        float mn = fmaxf(m, m4);
        float sc = __expf(m - mn);
        float p0 = __expf(e0 - mn), p1 = __expf(e1 - mn);
        float p2 = __expf(e2 - mn), p3 = __expf(e3 - mn);
        den = den * sc + ((p0 + p1) + (p2 + p3));
        acc = acc * sc + ((p0 * v0 + p1 * v1) + (p2 * v2 + p3 * v3));
        m = mn;
    }
    for (; i < end; ++i) {
        int s = srcs[i];
        float e = LRELU(asrc[s * H1 + hh] + ad);
        float hv = h1[s * F_MID + lane];
        float mn = fmaxf(m, e);
        float sc = __expf(m - mn);
        float p  = __expf(e - mn);
        den = den * sc + p;
        acc = acc * sc + p * hv;
        m = mn;
    }
    float inv = 1.f / (den + 1e-16f);
    float v = acc * inv + b1[lane];
    out1[n * F_MID + lane] = v > 0.f ? v : expm1f(v);   // ELU
}

// ---------------- GEMM2: h2 = out1 @ W2  [N,64] x [64,41] ----------------
__global__ __launch_bounds__(256) void gemm2_kernel(
    const float* __restrict__ out1, const float* __restrict__ W2,
    float* __restrict__ h2, int N)
{
    __shared__ float ws[F_MID * NC];
    for (int i = threadIdx.x; i < F_MID * NC; i += 256) ws[i] = W2[i];
    __syncthreads();
    int idx = blockIdx.x * blockDim.x + threadIdx.x;
    if (idx >= N * NC) return;
    int n = idx / NC, j = idx % NC;
    const float* row = out1 + n * F_MID;
    float acc = 0.f;
    #pragma unroll
    for (int k = 0; k < F_MID; ++k) acc += row[k] * ws[k * NC + j];
    h2[idx] = acc;
}

__global__ void attn2_kernel(const float* __restrict__ h2,
                             const float* __restrict__ attS,
                             const float* __restrict__ attD,
                             float* __restrict__ asrc, float* __restrict__ adst, int N)
{
    int n = blockIdx.x * blockDim.x + threadIdx.x;
    if (n >= N) return;
    float s = 0.f, d = 0.f;
    #pragma unroll
    for (int j = 0; j < NC; ++j) {
        float v = h2[n * NC + j];
        s += v * attS[j];
        d += v * attD[j];
    }
    asrc[n] = s;
    adst[n] = d;
}

// ------- layer-2 aggregation + log_softmax: one wave per node, online softmax -------
__global__ void agg2_kernel(const int* __restrict__ offs, const int* __restrict__ srcs,
                            const float* __restrict__ h2,
                            const float* __restrict__ asrc, const float* __restrict__ adst,
                            const float* __restrict__ b2,
                            float* __restrict__ out, int N)
{
    int wave = (blockIdx.x * blockDim.x + threadIdx.x) >> 6;
    int lane = threadIdx.x & 63;
    if (wave >= N) return;
    int n = wave;
    int beg = offs[n], end = offs[n + 1];
    float ad = adst[n];
    bool act = lane < NC;

    float m = -INFINITY, den = 0.f, acc = 0.f;
    int i = beg;
    for (; i + 4 <= end; i += 4) {
        int s0 = srcs[i], s1 = srcs[i + 1], s2 = srcs[i + 2], s3 = srcs[i + 3];
        float a0 = asrc[s0], a1 = asrc[s1], a2 = asrc[s2], a3 = asrc[s3];
        float v0 = act ? h2[s0 * NC + lane] : 0.f;
        float v1 = act ? h2[s1 * NC + lane] : 0.f;
        float v2 = act ? h2[s2 * NC + lane] : 0.f;
        float v3 = act ? h2[s3 * NC + lane] : 0.f;
        float e0 = LRELU(a0 + ad), e1 = LRELU(a1 + ad);
        float e2 = LRELU(a2 + ad), e3 = LRELU(a3 + ad);
        float m4 = fmaxf(fmaxf(e0, e1), fmaxf(e2, e3));
        float mn = fmaxf(m, m4);
        float sc = __expf(m - mn);
        float p0 = __expf(e0 - mn), p1 = __expf(e1 - mn);
        float p2 = __expf(e2 - mn), p3 = __expf(e3 - mn);
        den = den * sc + ((p0 + p1) + (p2 + p3));
        acc = acc * sc + ((p0 * v0 + p1 * v1) + (p2 * v2 + p3 * v3));
        m = mn;
    }
    for (; i < end; ++i) {
        int s = srcs[i];
        float e = LRELU(asrc[s] + ad);
        float hv = act ? h2[s * NC + lane] : 0.f;
        float mn = fmaxf(m, e);
        float sc = __expf(m - mn);
        float p  = __expf(e - mn);
        den = den * sc + p;
        acc = acc * sc + p * hv;
        m = mn;
    }
    float inv = 1.f / (den + 1e-16f);
    // logits; log_softmax across lanes 0..40
    float v = act ? acc * inv + b2[lane] : -INFINITY;
    float mm = v;
    #pragma unroll
    for (int o = 32; o > 0; o >>= 1) mm = fmaxf(mm, __shfl_xor(mm, o));
    float ex = act ? __expf(v - mm) : 0.f;
    float S = ex;
    #pragma unroll
    for (int o = 32; o > 0; o >>= 1) S += __shfl_xor(S, o);
    if (act) out[n * NC + lane] = v - mm - logf(S);
}

// ---------------- launch ----------------
extern "C" void kernel_launch(void* const* d_in, const int* in_sizes, int n_in,
                              void* d_out, int out_size, void* d_ws, size_t ws_size,
                              hipStream_t stream)
{
    const float* x     = (const float*)d_in[0];
    const int*   ei    = (const int*)  d_in[1];
    const float* W1    = (const float*)d_in[2];
    const float* attS1 = (const float*)d_in[3];
    const float* attD1 = (const float*)d_in[4];
    const float* b1    = (const float*)d_in[5];
    const float* W2    = (const float*)d_in[6];
    const float* attS2 = (const float*)d_in[7];
    const float* attD2 = (const float*)d_in[8];
    const float* b2    = (const float*)d_in[9];
    float* out = (float*)d_out;

    const int N = NN, E = NE;
    const int* src = ei;        // edge_index row 0
    const int* dst = ei + E;    // edge_index row 1

    char* p = (char*)d_ws;
    auto alloc = [&](size_t bytes) { char* r = p; p += (bytes + 255) & ~255ull; return r; };
    float* h1    = (float*)alloc((size_t)N * F_MID * 4);
    float* asrc1 = (float*)alloc((size_t)N * H1 * 4);
    float* adst1 = (float*)alloc((size_t)N * H1 * 4);
    float* out1  = (float*)alloc((size_t)N * F_MID * 4);
    float* h2    = (float*)alloc((size_t)N * NC * 4);
    float* asrc2 = (float*)alloc((size_t)N * 4);
    float* adst2 = (float*)alloc((size_t)N * 4);
    int*   deg   = (int*)alloc((size_t)2 * N * 4);    // deg + cursor contiguous
    int*   cursor= deg + N;
    int*   offs  = (int*)alloc((size_t)(N + 1) * 4);
    int*   srcs  = (int*)alloc((size_t)E * 4);

    hipMemsetAsync(deg, 0, (size_t)2 * N * 4, stream);

    gemm1_kernel<<<(N + 63) / 64, 256, 0, stream>>>(x, W1, h1, N);
    attn1_kernel<<<(N * H1 + 255) / 256, 256, 0, stream>>>(h1, attS1, attD1, asrc1, adst1, N);
    deg_kernel<<<(E + 255) / 256, 256, 0, stream>>>(dst, deg, E);
    scan_kernel<<<1, 1024, 0, stream>>>(deg, offs, N, E);
    scatter_kernel<<<(E + 255) / 256, 256, 0, stream>>>(src, dst, offs, cursor, srcs, E);
    agg1_kernel<<<(N * 64 + 255) / 256, 256, 0, stream>>>(offs, srcs, h1, asrc1, adst1, b1, out1, N);
    gemm2_kernel<<<(N * NC + 255) / 256, 256, 0, stream>>>(out1, W2, h2, N);
    attn2_kernel<<<(N + 255) / 256, 256, 0, stream>>>(h2, attS2, attD2, asrc2, adst2, N);
    agg2_kernel<<<(N * 64 + 255) / 256, 256, 0, stream>>>(offs, srcs, h2, asrc2, adst2, b2, out, N);
}

// Round 5
// 638.949 us; speedup vs baseline: 2.1319x; 1.2564x over previous
//
#include <hip/hip_runtime.h>
#include <math.h>

#define NN 100000
#define NE 1600000
#define F_IN 602
#define H1 8
#define C1 8
#define F_MID 64   // H1*C1
#define NC 41
#define NEG_SLOPE 0.2f
#define WT_LD 608  // padded K for bf16 W1-transposed

#define LRELU(x) fmaxf((x), NEG_SLOPE * (x))

typedef __attribute__((ext_vector_type(8))) short short8;
typedef __attribute__((ext_vector_type(4))) float f32x4;

__device__ inline unsigned short f2bf(float f) {
    unsigned u = __builtin_bit_cast(unsigned, f);
    unsigned r = (u + 0x7FFFu + ((u >> 16) & 1u)) >> 16;
    return (unsigned short)r;
}

// ---------------- W1 -> bf16 transposed padded [64][608] ----------------
__global__ void prep_wt_kernel(const float* __restrict__ W, unsigned short* __restrict__ Wt)
{
    int idx = blockIdx.x * blockDim.x + threadIdx.x;
    if (idx >= F_MID * WT_LD) return;
    int col = idx / WT_LD, k = idx % WT_LD;
    Wt[idx] = (k < F_IN) ? f2bf(W[k * F_MID + col]) : (unsigned short)0;
}

// ---------------- GEMM1 (MFMA bf16): h1 = x @ W1  [N,602]x[602,64] ----------------
// BM=128 rows/block, BK=32, 256 threads = 4 waves; wave w owns rows w*32..w*32+31.
__global__ __launch_bounds__(256) void gemm1_mfma(
    const float* __restrict__ x, const unsigned short* __restrict__ Wt,
    float* __restrict__ h, int N)
{
    __shared__ unsigned short As[128][40];  // 10240 B, stride 80B -> <=2-way conflicts
    __shared__ unsigned short Bs[64][40];   // 5120 B

    int t = threadIdx.x;
    int lane = t & 63;
    int w = t >> 6;
    int l16 = lane & 15, lg = lane >> 4;
    int n0 = blockIdx.x * 128;

    // A staging map: 2 threads per row, each covers 16 consecutive k (fp32 -> bf16)
    int arow = t >> 1;
    int acol16 = (t & 1) * 16;
    const float* xrow = x + (size_t)(n0 + arow) * F_IN;
    bool rowok = (n0 + arow) < N;

    // B staging map: thread t covers col=t>>2, 8 consecutive k
    int bcol = t >> 2;
    int bk8 = (t & 3) * 8;

    f32x4 acc[2][4] = {};

    for (int k0 = 0; k0 < F_IN; k0 += 32) {
        // ---- load to regs ----
        unsigned short abuf[16];
        if (rowok && (k0 + 32 <= F_IN)) {
            #pragma unroll
            for (int i = 0; i < 8; ++i) {
                float2 v = *(const float2*)(xrow + k0 + acol16 + i * 2);
                abuf[i * 2]     = f2bf(v.x);
                abuf[i * 2 + 1] = f2bf(v.y);
            }
        } else {
            #pragma unroll
            for (int i = 0; i < 16; ++i) {
                int k = k0 + acol16 + i;
                abuf[i] = (rowok && k < F_IN) ? f2bf(xrow[k]) : (unsigned short)0;
            }
        }
        uint4 bvec = *(const uint4*)(Wt + (size_t)bcol * WT_LD + k0 + bk8);

        __syncthreads();   // previous iteration's LDS reads complete
        *(uint4*)(&As[arow][acol16])     = *(uint4*)(&abuf[0]);
        *(uint4*)(&As[arow][acol16 + 8]) = *(uint4*)(&abuf[8]);
        *(uint4*)(&Bs[bcol][bk8])        = bvec;
        __syncthreads();   // LDS writes visible

        // ---- fragments + MFMA ----
        short8 afrag[2], bfrag[4];
        #pragma unroll
        for (int m = 0; m < 2; ++m)
            afrag[m] = *(const short8*)(&As[w * 32 + m * 16 + l16][lg * 8]);
        #pragma unroll
        for (int n = 0; n < 4; ++n)
            bfrag[n] = *(const short8*)(&Bs[n * 16 + l16][lg * 8]);
        #pragma unroll
        for (int m = 0; m < 2; ++m)
            #pragma unroll
            for (int n = 0; n < 4; ++n)
                acc[m][n] = __builtin_amdgcn_mfma_f32_16x16x32_bf16(
                    afrag[m], bfrag[n], acc[m][n], 0, 0, 0);
    }

    // epilogue: C/D layout col=lane&15, row=(lane>>4)*4+reg  (m89-verified)
    #pragma unroll
    for (int m = 0; m < 2; ++m) {
        #pragma unroll
        for (int r = 0; r < 4; ++r) {
            int row = n0 + w * 32 + m * 16 + lg * 4 + r;
            if (row < N) {
                #pragma unroll
                for (int n = 0; n < 4; ++n)
                    h[(size_t)row * F_MID + n * 16 + l16] = acc[m][n][r];
            }
        }
    }
}

// ---------------- attention coefficients layer 1 ----------------
__global__ void attn1_kernel(const float* __restrict__ h,
                             const float* __restrict__ attS,
                             const float* __restrict__ attD,
                             float* __restrict__ asrc, float* __restrict__ adst, int N)
{
    int idx = blockIdx.x * blockDim.x + threadIdx.x;   // n*8 + head
    if (idx >= N * H1) return;
    int n = idx >> 3, hh = idx & 7;
    float s = 0.f, d = 0.f;
    #pragma unroll
    for (int c = 0; c < C1; ++c) {
        float v = h[n * F_MID + hh * C1 + c];
        s += v * attS[hh * C1 + c];
        d += v * attD[hh * C1 + c];
    }
    asrc[idx] = s;
    adst[idx] = d;
}

// ---------------- CSR build ----------------
__global__ void deg_kernel(const int* __restrict__ dst, int* __restrict__ deg, int E)
{
    int e = blockIdx.x * blockDim.x + threadIdx.x;
    if (e < E) atomicAdd(&deg[dst[e]], 1);
}

__global__ __launch_bounds__(1024) void scan_kernel(const int* __restrict__ deg,
                                                    int* __restrict__ offs, int N, int E)
{
    __shared__ int part[1024];
    __shared__ int pref[1024];
    int t = threadIdx.x;
    int chunk = (N + 1023) / 1024;
    int b = t * chunk, e = min(N, b + chunk);
    int s = 0;
    for (int i = b; i < e; ++i) s += deg[i];
    part[t] = s;
    __syncthreads();
    if (t == 0) {
        int run = 0;
        for (int i = 0; i < 1024; ++i) { pref[i] = run; run += part[i]; }
    }
    __syncthreads();
    int run = pref[t];
    for (int i = b; i < e; ++i) { offs[i] = run; run += deg[i]; }
    if (t == 1023) offs[N] = E;
}

__global__ void scatter_kernel(const int* __restrict__ src, const int* __restrict__ dst,
                               const int* __restrict__ offs, int* __restrict__ cursor,
                               int* __restrict__ srcs, int E)
{
    int e = blockIdx.x * blockDim.x + threadIdx.x;
    if (e < E) {
        int d = dst[e];
        int pos = offs[d] + atomicAdd(&cursor[d], 1);
        srcs[pos] = src[e];
    }
}

// ------- layer-1 aggregation + ELU: one wave per node, online softmax, 4-edge batches -------
__global__ void agg1_kernel(const int* __restrict__ offs, const int* __restrict__ srcs,
                            const float* __restrict__ h1,
                            const float* __restrict__ asrc, const float* __restrict__ adst,
                            const float* __restrict__ b1,
                            float* __restrict__ out1, int N)
{
    int wave = (blockIdx.x * blockDim.x + threadIdx.x) >> 6;
    int lane = threadIdx.x & 63;
    if (wave >= N) return;
    int n = wave;
    int hh = lane >> 3;                 // head
    int beg = offs[n], end = offs[n + 1];
    float ad = adst[n * H1 + hh];

    float m = -INFINITY, den = 0.f, acc = 0.f;
    int i = beg;
    for (; i + 4 <= end; i += 4) {
        int s0 = srcs[i], s1 = srcs[i + 1], s2 = srcs[i + 2], s3 = srcs[i + 3];
        float a0 = asrc[s0 * H1 + hh], a1 = asrc[s1 * H1 + hh];
        float a2 = asrc[s2 * H1 + hh], a3 = asrc[s3 * H1 + hh];
        float v0 = h1[s0 * F_MID + lane], v1 = h1[s1 * F_MID + lane];
        float v2 = h1[s2 * F_MID + lane], v3 = h1[s3 * F_MID + lane];
        float e0 = LRELU(a0 + ad), e1 = LRELU(a1 + ad);
        float e2 = LRELU(a2 + ad), e3 = LRELU(a3 + ad);
        float m4 = fmaxf(fmaxf(e0, e1), fmaxf(e2, e3));
        float mn = fmaxf(m, m4);
        float sc = __expf(m - mn);
        float p0 = __expf(e0 - mn), p1 = __expf(e1 - mn);
        float p2 = __expf(e2 - mn), p3 = __expf(e3 - mn);
        den = den * sc + ((p0 + p1) + (p2 + p3));
        acc = acc * sc + ((p0 * v0 + p1 * v1) + (p2 * v2 + p3 * v3));
        m = mn;
    }
    for (; i < end; ++i) {
        int s = srcs[i];
        float e = LRELU(asrc[s * H1 + hh] + ad);
        float hv = h1[s * F_MID + lane];
        float mn = fmaxf(m, e);
        float sc = __expf(m - mn);
        float p  = __expf(e - mn);
        den = den * sc + p;
        acc = acc * sc + p * hv;
        m = mn;
    }
    float inv = 1.f / (den + 1e-16f);
    float v = acc * inv + b1[lane];
    out1[n * F_MID + lane] = v > 0.f ? v : expm1f(v);   // ELU
}

// ---------------- GEMM2: h2 = out1 @ W2  [N,64] x [64,41] ----------------
__global__ __launch_bounds__(256) void gemm2_kernel(
    const float* __restrict__ out1, const float* __restrict__ W2,
    float* __restrict__ h2, int N)
{
    __shared__ float ws[F_MID * NC];
    for (int i = threadIdx.x; i < F_MID * NC; i += 256) ws[i] = W2[i];
    __syncthreads();
    int idx = blockIdx.x * blockDim.x + threadIdx.x;
    if (idx >= N * NC) return;
    int n = idx / NC, j = idx % NC;
    const float* row = out1 + n * F_MID;
    float acc = 0.f;
    #pragma unroll
    for (int k = 0; k < F_MID; ++k) acc += row[k] * ws[k * NC + j];
    h2[idx] = acc;
}

__global__ void attn2_kernel(const float* __restrict__ h2,
                             const float* __restrict__ attS,
                             const float* __restrict__ attD,
                             float* __restrict__ asrc, float* __restrict__ adst, int N)
{
    int n = blockIdx.x * blockDim.x + threadIdx.x;
    if (n >= N) return;
    float s = 0.f, d = 0.f;
    #pragma unroll
    for (int j = 0; j < NC; ++j) {
        float v = h2[n * NC + j];
        s += v * attS[j];
        d += v * attD[j];
    }
    asrc[n] = s;
    adst[n] = d;
}

// ------- layer-2 aggregation + log_softmax: one wave per node, online softmax -------
__global__ void agg2_kernel(const int* __restrict__ offs, const int* __restrict__ srcs,
                            const float* __restrict__ h2,
                            const float* __restrict__ asrc, const float* __restrict__ adst,
                            const float* __restrict__ b2,
                            float* __restrict__ out, int N)
{
    int wave = (blockIdx.x * blockDim.x + threadIdx.x) >> 6;
    int lane = threadIdx.x & 63;
    if (wave >= N) return;
    int n = wave;
    int beg = offs[n], end = offs[n + 1];
    float ad = adst[n];
    bool act = lane < NC;

    float m = -INFINITY, den = 0.f, acc = 0.f;
    int i = beg;
    for (; i + 4 <= end; i += 4) {
        int s0 = srcs[i], s1 = srcs[i + 1], s2 = srcs[i + 2], s3 = srcs[i + 3];
        float a0 = asrc[s0], a1 = asrc[s1], a2 = asrc[s2], a3 = asrc[s3];
        float v0 = act ? h2[s0 * NC + lane] : 0.f;
        float v1 = act ? h2[s1 * NC + lane] : 0.f;
        float v2 = act ? h2[s2 * NC + lane] : 0.f;
        float v3 = act ? h2[s3 * NC + lane] : 0.f;
        float e0 = LRELU(a0 + ad), e1 = LRELU(a1 + ad);
        float e2 = LRELU(a2 + ad), e3 = LRELU(a3 + ad);
        float m4 = fmaxf(fmaxf(e0, e1), fmaxf(e2, e3));
        float mn = fmaxf(m, m4);
        float sc = __expf(m - mn);
        float p0 = __expf(e0 - mn), p1 = __expf(e1 - mn);
        float p2 = __expf(e2 - mn), p3 = __expf(e3 - mn);
        den = den * sc + ((p0 + p1) + (p2 + p3));
        acc = acc * sc + ((p0 * v0 + p1 * v1) + (p2 * v2 + p3 * v3));
        m = mn;
    }
    for (; i < end; ++i) {
        int s = srcs[i];
        float e = LRELU(asrc[s] + ad);
        float hv = act ? h2[s * NC + lane] : 0.f;
        float mn = fmaxf(m, e);
        float sc = __expf(m - mn);
        float p  = __expf(e - mn);
        den = den * sc + p;
        acc = acc * sc + p * hv;
        m = mn;
    }
    float inv = 1.f / (den + 1e-16f);
    float v = act ? acc * inv + b2[lane] : -INFINITY;
    float mm = v;
    #pragma unroll
    for (int o = 32; o > 0; o >>= 1) mm = fmaxf(mm, __shfl_xor(mm, o));
    float ex = act ? __expf(v - mm) : 0.f;
    float S = ex;
    #pragma unroll
    for (int o = 32; o > 0; o >>= 1) S += __shfl_xor(S, o);
    if (act) out[n * NC + lane] = v - mm - logf(S);
}

// ---------------- launch ----------------
extern "C" void kernel_launch(void* const* d_in, const int* in_sizes, int n_in,
                              void* d_out, int out_size, void* d_ws, size_t ws_size,
                              hipStream_t stream)
{
    const float* x     = (const float*)d_in[0];
    const int*   ei    = (const int*)  d_in[1];
    const float* W1    = (const float*)d_in[2];
    const float* attS1 = (const float*)d_in[3];
    const float* attD1 = (const float*)d_in[4];
    const float* b1    = (const float*)d_in[5];
    const float* W2    = (const float*)d_in[6];
    const float* attS2 = (const float*)d_in[7];
    const float* attD2 = (const float*)d_in[8];
    const float* b2    = (const float*)d_in[9];
    float* out = (float*)d_out;

    const int N = NN, E = NE;
    const int* src = ei;        // edge_index row 0
    const int* dst = ei + E;    // edge_index row 1

    char* p = (char*)d_ws;
    auto alloc = [&](size_t bytes) { char* r = p; p += (bytes + 255) & ~255ull; return r; };
    float* h1    = (float*)alloc((size_t)N * F_MID * 4);
    float* asrc1 = (float*)alloc((size_t)N * H1 * 4);
    float* adst1 = (float*)alloc((size_t)N * H1 * 4);
    float* out1  = (float*)alloc((size_t)N * F_MID * 4);
    float* h2    = (float*)alloc((size_t)N * NC * 4);
    float* asrc2 = (float*)alloc((size_t)N * 4);
    float* adst2 = (float*)alloc((size_t)N * 4);
    int*   deg   = (int*)alloc((size_t)2 * N * 4);    // deg + cursor contiguous
    int*   cursor= deg + N;
    int*   offs  = (int*)alloc((size_t)(N + 1) * 4);
    int*   srcs  = (int*)alloc((size_t)E * 4);
    unsigned short* Wt = (unsigned short*)alloc((size_t)F_MID * WT_LD * 2);

    hipMemsetAsync(deg, 0, (size_t)2 * N * 4, stream);

    prep_wt_kernel<<<(F_MID * WT_LD + 255) / 256, 256, 0, stream>>>(W1, Wt);
    gemm1_mfma<<<(N + 127) / 128, 256, 0, stream>>>(x, Wt, h1, N);
    attn1_kernel<<<(N * H1 + 255) / 256, 256, 0, stream>>>(h1, attS1, attD1, asrc1, adst1, N);
    deg_kernel<<<(E + 255) / 256, 256, 0, stream>>>(dst, deg, E);
    scan_kernel<<<1, 1024, 0, stream>>>(deg, offs, N, E);
    scatter_kernel<<<(E + 255) / 256, 256, 0, stream>>>(src, dst, offs, cursor, srcs, E);
    agg1_kernel<<<(N * 64 + 255) / 256, 256, 0, stream>>>(offs, srcs, h1, asrc1, adst1, b1, out1, N);
    gemm2_kernel<<<(N * NC + 255) / 256, 256, 0, stream>>>(out1, W2, h2, N);
    attn2_kernel<<<(N + 255) / 256, 256, 0, stream>>>(h2, attS2, attD2, asrc2, adst2, N);
    agg2_kernel<<<(N * 64 + 255) / 256, 256, 0, stream>>>(offs, srcs, h2, asrc2, adst2, b2, out, N);
}

// Round 6
// 485.466 us; speedup vs baseline: 2.8059x; 1.3162x over previous
//
#include <hip/hip_runtime.h>
#include <math.h>

#define NN 100000
#define NE 1600000
#define F_IN 602
#define H1 8
#define C1 8
#define F_MID 64   // H1*C1
#define NC 41
#define NEG_SLOPE 0.2f
#define WT_LD 608  // padded K for bf16 W1-transposed

#define LRELU(x) fmaxf((x), NEG_SLOPE * (x))

typedef __attribute__((ext_vector_type(8))) short short8;
typedef __attribute__((ext_vector_type(4))) float f32x4;

__device__ inline unsigned short f2bf(float f) {
    unsigned u = __builtin_bit_cast(unsigned, f);
    unsigned r = (u + 0x7FFFu + ((u >> 16) & 1u)) >> 16;
    return (unsigned short)r;
}

// ---------------- W1 -> bf16 transposed padded [64][608] ----------------
__global__ void prep_wt_kernel(const float* __restrict__ W, unsigned short* __restrict__ Wt)
{
    int idx = blockIdx.x * blockDim.x + threadIdx.x;
    if (idx >= F_MID * WT_LD) return;
    int col = idx / WT_LD, k = idx % WT_LD;
    Wt[idx] = (k < F_IN) ? f2bf(W[k * F_MID + col]) : (unsigned short)0;
}

// ---------------- GEMM1 (MFMA bf16): h1 = x @ W1  [N,602]x[602,64] ----------------
__global__ __launch_bounds__(256) void gemm1_mfma(
    const float* __restrict__ x, const unsigned short* __restrict__ Wt,
    float* __restrict__ h, int N)
{
    __shared__ unsigned short As[128][40];  // stride 80B -> <=2-way conflicts
    __shared__ unsigned short Bs[64][40];

    int t = threadIdx.x;
    int lane = t & 63;
    int w = t >> 6;
    int l16 = lane & 15, lg = lane >> 4;
    int n0 = blockIdx.x * 128;

    int arow = t >> 1;
    int acol16 = (t & 1) * 16;
    const float* xrow = x + (size_t)(n0 + arow) * F_IN;
    bool rowok = (n0 + arow) < N;

    int bcol = t >> 2;
    int bk8 = (t & 3) * 8;

    f32x4 acc[2][4] = {};

    for (int k0 = 0; k0 < F_IN; k0 += 32) {
        unsigned short abuf[16];
        if (rowok && (k0 + 32 <= F_IN)) {
            #pragma unroll
            for (int i = 0; i < 8; ++i) {
                float2 v = *(const float2*)(xrow + k0 + acol16 + i * 2);
                abuf[i * 2]     = f2bf(v.x);
                abuf[i * 2 + 1] = f2bf(v.y);
            }
        } else {
            #pragma unroll
            for (int i = 0; i < 16; ++i) {
                int k = k0 + acol16 + i;
                abuf[i] = (rowok && k < F_IN) ? f2bf(xrow[k]) : (unsigned short)0;
            }
        }
        uint4 bvec = *(const uint4*)(Wt + (size_t)bcol * WT_LD + k0 + bk8);

        __syncthreads();
        *(uint4*)(&As[arow][acol16])     = *(uint4*)(&abuf[0]);
        *(uint4*)(&As[arow][acol16 + 8]) = *(uint4*)(&abuf[8]);
        *(uint4*)(&Bs[bcol][bk8])        = bvec;
        __syncthreads();

        short8 afrag[2], bfrag[4];
        #pragma unroll
        for (int m = 0; m < 2; ++m)
            afrag[m] = *(const short8*)(&As[w * 32 + m * 16 + l16][lg * 8]);
        #pragma unroll
        for (int n = 0; n < 4; ++n)
            bfrag[n] = *(const short8*)(&Bs[n * 16 + l16][lg * 8]);
        #pragma unroll
        for (int m = 0; m < 2; ++m)
            #pragma unroll
            for (int n = 0; n < 4; ++n)
                acc[m][n] = __builtin_amdgcn_mfma_f32_16x16x32_bf16(
                    afrag[m], bfrag[n], acc[m][n], 0, 0, 0);
    }

    #pragma unroll
    for (int m = 0; m < 2; ++m) {
        #pragma unroll
        for (int r = 0; r < 4; ++r) {
            int row = n0 + w * 32 + m * 16 + lg * 4 + r;
            if (row < N) {
                #pragma unroll
                for (int n = 0; n < 4; ++n)
                    h[(size_t)row * F_MID + n * 16 + l16] = acc[m][n][r];
            }
        }
    }
}

// ---------------- attention coefficients layer 1 ----------------
__global__ void attn1_kernel(const float* __restrict__ h,
                             const float* __restrict__ attS,
                             const float* __restrict__ attD,
                             float* __restrict__ asrc, float* __restrict__ adst, int N)
{
    int idx = blockIdx.x * blockDim.x + threadIdx.x;   // n*8 + head
    if (idx >= N * H1) return;
    int n = idx >> 3, hh = idx & 7;
    float s = 0.f, d = 0.f;
    #pragma unroll
    for (int c = 0; c < C1; ++c) {
        float v = h[n * F_MID + hh * C1 + c];
        s += v * attS[hh * C1 + c];
        d += v * attD[hh * C1 + c];
    }
    asrc[idx] = s;
    adst[idx] = d;
}

// ---------------- CSR build ----------------
__global__ void deg_kernel(const int* __restrict__ dst, int* __restrict__ deg, int E)
{
    int e = blockIdx.x * blockDim.x + threadIdx.x;
    if (e < E) atomicAdd(&deg[dst[e]], 1);
}

// hierarchical scan: 1024 elements per block (64 threads x 16)
__global__ void scan1_kernel(const int* __restrict__ deg, int* __restrict__ bsum, int N)
{
    int b = blockIdx.x, t = threadIdx.x;
    int base = b * 1024 + t * 16;
    int s = 0;
    #pragma unroll
    for (int i = 0; i < 16; ++i) { int idx = base + i; if (idx < N) s += deg[idx]; }
    #pragma unroll
    for (int o = 32; o > 0; o >>= 1) s += __shfl_down(s, o);
    if (t == 0) bsum[b] = s;
}

__global__ void scan2_kernel(const int* __restrict__ bsum, int* __restrict__ boff,
                             int nb, int* __restrict__ offs, int N, int E)
{
    __shared__ int buf[128];
    int t = threadIdx.x;
    int v = (t < nb) ? bsum[t] : 0;
    buf[t] = v;
    __syncthreads();
    for (int o = 1; o < 128; o <<= 1) {
        int u = (t >= o) ? buf[t - o] : 0;
        __syncthreads();
        buf[t] += u;
        __syncthreads();
    }
    if (t < nb) boff[t] = buf[t] - v;    // exclusive
    if (t == 0) offs[N] = E;
}

__global__ void scan3_kernel(const int* __restrict__ deg, const int* __restrict__ boff,
                             int* __restrict__ offs, int N)
{
    int b = blockIdx.x, t = threadIdx.x;
    int base = b * 1024 + t * 16;
    int loc[16];
    int s = 0;
    #pragma unroll
    for (int i = 0; i < 16; ++i) {
        int idx = base + i;
        loc[i] = (idx < N) ? deg[idx] : 0;
        s += loc[i];
    }
    int inc = s;
    #pragma unroll
    for (int o = 1; o < 64; o <<= 1) {
        int u = __shfl_up(inc, o);
        if (t >= o) inc += u;
    }
    int run = inc - s + boff[b];
    #pragma unroll
    for (int i = 0; i < 16; ++i) {
        int idx = base + i;
        if (idx < N) offs[idx] = run;
        run += loc[i];
    }
}

__global__ void scatter_kernel(const int* __restrict__ src, const int* __restrict__ dst,
                               const int* __restrict__ offs, int* __restrict__ cursor,
                               int* __restrict__ srcs, int E)
{
    int e = blockIdx.x * blockDim.x + threadIdx.x;
    if (e < E) {
        int d = dst[e];
        int pos = offs[d] + atomicAdd(&cursor[d], 1);
        srcs[pos] = src[e];
    }
}

// ------- layer-1 aggregation + ELU: one wave per node, online softmax, 4-edge batches -------
__global__ void agg1_kernel(const int* __restrict__ offs, const int* __restrict__ srcs,
                            const float* __restrict__ h1,
                            const float* __restrict__ asrc, const float* __restrict__ adst,
                            const float* __restrict__ b1,
                            float* __restrict__ out1, int N)
{
    int wave = (blockIdx.x * blockDim.x + threadIdx.x) >> 6;
    int lane = threadIdx.x & 63;
    if (wave >= N) return;
    int n = wave;
    int hh = lane >> 3;                 // head
    int beg = offs[n], end = offs[n + 1];
    float ad = adst[n * H1 + hh];

    float m = -INFINITY, den = 0.f, acc = 0.f;
    int i = beg;
    for (; i + 4 <= end; i += 4) {
        int s0 = srcs[i], s1 = srcs[i + 1], s2 = srcs[i + 2], s3 = srcs[i + 3];
        float a0 = asrc[s0 * H1 + hh], a1 = asrc[s1 * H1 + hh];
        float a2 = asrc[s2 * H1 + hh], a3 = asrc[s3 * H1 + hh];
        float v0 = h1[s0 * F_MID + lane], v1 = h1[s1 * F_MID + lane];
        float v2 = h1[s2 * F_MID + lane], v3 = h1[s3 * F_MID + lane];
        float e0 = LRELU(a0 + ad), e1 = LRELU(a1 + ad);
        float e2 = LRELU(a2 + ad), e3 = LRELU(a3 + ad);
        float m4 = fmaxf(fmaxf(e0, e1), fmaxf(e2, e3));
        float mn = fmaxf(m, m4);
        float sc = __expf(m - mn);
        float p0 = __expf(e0 - mn), p1 = __expf(e1 - mn);
        float p2 = __expf(e2 - mn), p3 = __expf(e3 - mn);
        den = den * sc + ((p0 + p1) + (p2 + p3));
        acc = acc * sc + ((p0 * v0 + p1 * v1) + (p2 * v2 + p3 * v3));
        m = mn;
    }
    for (; i < end; ++i) {
        int s = srcs[i];
        float e = LRELU(asrc[s * H1 + hh] + ad);
        float hv = h1[s * F_MID + lane];
        float mn = fmaxf(m, e);
        float sc = __expf(m - mn);
        float p  = __expf(e - mn);
        den = den * sc + p;
        acc = acc * sc + p * hv;
        m = mn;
    }
    float inv = 1.f / (den + 1e-16f);
    float v = acc * inv + b1[lane];
    out1[n * F_MID + lane] = v > 0.f ? v : expm1f(v);   // ELU
}

// ---------------- GEMM2: h2 = out1 @ W2  [N,64] x [64,41] ----------------
__global__ __launch_bounds__(256) void gemm2_kernel(
    const float* __restrict__ out1, const float* __restrict__ W2,
    float* __restrict__ h2, int N)
{
    __shared__ float ws[F_MID * NC];
    for (int i = threadIdx.x; i < F_MID * NC; i += 256) ws[i] = W2[i];
    __syncthreads();
    int idx = blockIdx.x * blockDim.x + threadIdx.x;
    if (idx >= N * NC) return;
    int n = idx / NC, j = idx % NC;
    const float* row = out1 + n * F_MID;
    float acc = 0.f;
    #pragma unroll
    for (int k = 0; k < F_MID; ++k) acc += row[k] * ws[k * NC + j];
    h2[idx] = acc;
}

__global__ void attn2_kernel(const float* __restrict__ h2,
                             const float* __restrict__ attS,
                             const float* __restrict__ attD,
                             float* __restrict__ asrc, float* __restrict__ adst, int N)
{
    int n = blockIdx.x * blockDim.x + threadIdx.x;
    if (n >= N) return;
    float s = 0.f, d = 0.f;
    #pragma unroll
    for (int j = 0; j < NC; ++j) {
        float v = h2[n * NC + j];
        s += v * attS[j];
        d += v * attD[j];
    }
    asrc[n] = s;
    adst[n] = d;
}

// ------- layer-2 aggregation + log_softmax: one wave per node, online softmax -------
__global__ void agg2_kernel(const int* __restrict__ offs, const int* __restrict__ srcs,
                            const float* __restrict__ h2,
                            const float* __restrict__ asrc, const float* __restrict__ adst,
                            const float* __restrict__ b2,
                            float* __restrict__ out, int N)
{
    int wave = (blockIdx.x * blockDim.x + threadIdx.x) >> 6;
    int lane = threadIdx.x & 63;
    if (wave >= N) return;
    int n = wave;
    int beg = offs[n], end = offs[n + 1];
    float ad = adst[n];
    bool act = lane < NC;

    float m = -INFINITY, den = 0.f, acc = 0.f;
    int i = beg;
    for (; i + 4 <= end; i += 4) {
        int s0 = srcs[i], s1 = srcs[i + 1], s2 = srcs[i + 2], s3 = srcs[i + 3];
        float a0 = asrc[s0], a1 = asrc[s1], a2 = asrc[s2], a3 = asrc[s3];
        float v0 = act ? h2[s0 * NC + lane] : 0.f;
        float v1 = act ? h2[s1 * NC + lane] : 0.f;
        float v2 = act ? h2[s2 * NC + lane] : 0.f;
        float v3 = act ? h2[s3 * NC + lane] : 0.f;
        float e0 = LRELU(a0 + ad), e1 = LRELU(a1 + ad);
        float e2 = LRELU(a2 + ad), e3 = LRELU(a3 + ad);
        float m4 = fmaxf(fmaxf(e0, e1), fmaxf(e2, e3));
        float mn = fmaxf(m, m4);
        float sc = __expf(m - mn);
        float p0 = __expf(e0 - mn), p1 = __expf(e1 - mn);
        float p2 = __expf(e2 - mn), p3 = __expf(e3 - mn);
        den = den * sc + ((p0 + p1) + (p2 + p3));
        acc = acc * sc + ((p0 * v0 + p1 * v1) + (p2 * v2 + p3 * v3));
        m = mn;
    }
    for (; i < end; ++i) {
        int s = srcs[i];
        float e = LRELU(asrc[s] + ad);
        float hv = act ? h2[s * NC + lane] : 0.f;
        float mn = fmaxf(m, e);
        float sc = __expf(m - mn);
        float p  = __expf(e - mn);
        den = den * sc + p;
        acc = acc * sc + p * hv;
        m = mn;
    }
    float inv = 1.f / (den + 1e-16f);
    float v = act ? acc * inv + b2[lane] : -INFINITY;
    float mm = v;
    #pragma unroll
    for (int o = 32; o > 0; o >>= 1) mm = fmaxf(mm, __shfl_xor(mm, o));
    float ex = act ? __expf(v - mm) : 0.f;
    float S = ex;
    #pragma unroll
    for (int o = 32; o > 0; o >>= 1) S += __shfl_xor(S, o);
    if (act) out[n * NC + lane] = v - mm - logf(S);
}

// ---------------- launch ----------------
extern "C" void kernel_launch(void* const* d_in, const int* in_sizes, int n_in,
                              void* d_out, int out_size, void* d_ws, size_t ws_size,
                              hipStream_t stream)
{
    const float* x     = (const float*)d_in[0];
    const int*   ei    = (const int*)  d_in[1];
    const float* W1    = (const float*)d_in[2];
    const float* attS1 = (const float*)d_in[3];
    const float* attD1 = (const float*)d_in[4];
    const float* b1    = (const float*)d_in[5];
    const float* W2    = (const float*)d_in[6];
    const float* attS2 = (const float*)d_in[7];
    const float* attD2 = (const float*)d_in[8];
    const float* b2    = (const float*)d_in[9];
    float* out = (float*)d_out;

    const int N = NN, E = NE;
    const int* src = ei;        // edge_index row 0
    const int* dst = ei + E;    // edge_index row 1

    char* p = (char*)d_ws;
    auto alloc = [&](size_t bytes) { char* r = p; p += (bytes + 255) & ~255ull; return r; };
    float* h1    = (float*)alloc((size_t)N * F_MID * 4);
    float* asrc1 = (float*)alloc((size_t)N * H1 * 4);
    float* adst1 = (float*)alloc((size_t)N * H1 * 4);
    float* out1  = (float*)alloc((size_t)N * F_MID * 4);
    float* h2    = (float*)alloc((size_t)N * NC * 4);
    float* asrc2 = (float*)alloc((size_t)N * 4);
    float* adst2 = (float*)alloc((size_t)N * 4);
    int*   deg   = (int*)alloc((size_t)2 * N * 4);    // deg + cursor contiguous
    int*   cursor= deg + N;
    int*   offs  = (int*)alloc((size_t)(N + 1) * 4);
    int*   srcs  = (int*)alloc((size_t)E * 4);
    unsigned short* Wt = (unsigned short*)alloc((size_t)F_MID * WT_LD * 2);
    const int NB = (N + 1023) / 1024;                 // 98 scan blocks
    int*   bsum  = (int*)alloc((size_t)NB * 4);
    int*   boff  = (int*)alloc((size_t)NB * 4);

    hipMemsetAsync(deg, 0, (size_t)2 * N * 4, stream);

    prep_wt_kernel<<<(F_MID * WT_LD + 255) / 256, 256, 0, stream>>>(W1, Wt);
    gemm1_mfma<<<(N + 127) / 128, 256, 0, stream>>>(x, Wt, h1, N);
    attn1_kernel<<<(N * H1 + 255) / 256, 256, 0, stream>>>(h1, attS1, attD1, asrc1, adst1, N);
    deg_kernel<<<(E + 255) / 256, 256, 0, stream>>>(dst, deg, E);
    scan1_kernel<<<NB, 64, 0, stream>>>(deg, bsum, N);
    scan2_kernel<<<1, 128, 0, stream>>>(bsum, boff, NB, offs, N, E);
    scan3_kernel<<<NB, 64, 0, stream>>>(deg, boff, offs, N);
    scatter_kernel<<<(E + 255) / 256, 256, 0, stream>>>(src, dst, offs, cursor, srcs, E);
    agg1_kernel<<<(N * 64 + 255) / 256, 256, 0, stream>>>(offs, srcs, h1, asrc1, adst1, b1, out1, N);
    gemm2_kernel<<<(N * NC + 255) / 256, 256, 0, stream>>>(out1, W2, h2, N);
    attn2_kernel<<<(N + 255) / 256, 256, 0, stream>>>(h2, attS2, attD2, asrc2, adst2, N);
    agg2_kernel<<<(N * 64 + 255) / 256, 256, 0, stream>>>(offs, srcs, h2, asrc2, adst2, b2, out, N);
}